// Round 4
// baseline (2259.347 us; speedup 1.0000x reference)
//
#include <hip/hip_runtime.h>

// CRF forward on MI355X — R3: MFMA-based multi-batch scan.
// 4 blocks x 256 threads; 16 batches per block. Per step: V'(256x16) = E(256x256)·V(256x16)
// via v_mfma_f32_16x16x32_f16 (E fragments resident in VGPRs). Normalizer T_b = sum_k (E·V)[k,b]
// computed as an extra MFMA tile with A-rows = CE (column sums of E): every lane holds T_b
// locally -> no shuffles, no reduction, ONE barrier per step. Per-batch mask via register-kept
// V slices. Exact scale bookkeeping Lam_b += log T_b.

typedef _Float16 h8 __attribute__((ext_vector_type(8)));
typedef _Float16 h4 __attribute__((ext_vector_type(4)));
typedef float    f4 __attribute__((ext_vector_type(4)));

#define TT 2048
#define KK 256
#define NB 16          // batches per block
#define SOS_IDX 2
#define VSTR 264       // fp16 elems per V row: 256 + 8 pad (bank spread)

#define MFMA16(a, b, c) __builtin_amdgcn_mfma_f32_16x16x32_f16((a), (b), (c), 0, 0, 0)

__global__ __launch_bounds__(256, 1)
void crf_fwd_kernel(const float* __restrict__ y, const float* __restrict__ mask,
                    const float* __restrict__ trans, float* __restrict__ out) {
    const int bi   = blockIdx.x;
    const int b0   = bi * NB;
    const int tid  = threadIdx.x;
    const int w    = tid >> 6;     // wave 0..3 -> state tiles 4w..4w+3
    const int lane = tid & 63;
    const int bl   = lane & 15;    // batch column (MFMA N index)
    const int g    = lane >> 4;    // quad (MFMA K/M group)

    __shared__ _Float16 Vb[2][NB][VSTR];   // double-buffered V, layout [batch][state]
    __shared__ _Float16 CEh[KK];

    // ---- CE[j] = sum_k exp(trans[k][j])  (fully coalesced across 256 threads)
    float ce = 0.f;
    for (int k = 0; k < KK; ++k) ce += __expf(trans[(size_t)k * KK + tid]);

    // ---- zero V[0]; publish CE
    for (int idx = tid; idx < NB * VSTR; idx += 256) (&Vb[0][0][0])[idx] = (_Float16)0.f;
    CEh[tid] = (_Float16)ce;
    __syncthreads();
    if (tid < NB) Vb[0][tid][SOS_IDX] = (_Float16)1.f;   // V0 = one-hot(SOS) per batch

    // ---- E fragments (A-operand): ea[i][kt] = exp(trans[m][kt*32+g*8+j]), m=(4w+i)*16+bl
    h8 ea[4][8];
    #pragma unroll
    for (int i = 0; i < 4; ++i) {
        const int m = (w * 4 + i) * 16 + bl;
        const float* tr = trans + (size_t)m * KK;
        #pragma unroll
        for (int kt = 0; kt < 8; ++kt) {
            const int k0 = kt * 32 + g * 8;
            float4 v0 = *(const float4*)(tr + k0);
            float4 v1 = *(const float4*)(tr + k0 + 4);
            h8 a;
            a[0] = (_Float16)__expf(v0.x); a[1] = (_Float16)__expf(v0.y);
            a[2] = (_Float16)__expf(v0.z); a[3] = (_Float16)__expf(v0.w);
            a[4] = (_Float16)__expf(v1.x); a[5] = (_Float16)__expf(v1.y);
            a[6] = (_Float16)__expf(v1.z); a[7] = (_Float16)__expf(v1.w);
            ea[i][kt] = a;
        }
    }
    __syncthreads();   // one-hot + CEh visible

    // ---- T-tile A fragment: all rows = CE  ->  every lane's acc = T_b
    h8 at[8];
    #pragma unroll
    for (int kt = 0; kt < 8; ++kt) at[kt] = *(const h8*)&CEh[kt * 32 + g * 8];

    // ---- per-lane kept V slices (for masked batches): tile i rows k0w..k0w+3, col bl
    h4 keep[4];
    #pragma unroll
    for (int i = 0; i < 4; ++i) {
        const int k0w = (w * 4 + i) * 16 + g * 4;
        h4 kv;
        #pragma unroll
        for (int r = 0; r < 4; ++r) kv[r] = (_Float16)((k0w + r == SOS_IDX) ? 1.f : 0.f);
        keep[i] = kv;
    }

    // ---- prefetch t=0 emissions + mask
    const float* ybase = y + (size_t)(b0 + bl) * TT * KK;
    const float* mbase = mask + (size_t)(b0 + bl) * TT;
    float4 yv[4];
    #pragma unroll
    for (int i = 0; i < 4; ++i) yv[i] = *(const float4*)(ybase + (w * 4 + i) * 16 + g * 4);
    float mv = mbase[0];

    float Lam = 0.f;
    int cur = 0;

    for (int t = 0; t < TT; ++t) {
        // emissions for this step (VALU; overlaps MFMA pipe)
        float eyv[4][4];
        #pragma unroll
        for (int i = 0; i < 4; ++i) {
            eyv[i][0] = __expf(yv[i].x); eyv[i][1] = __expf(yv[i].y);
            eyv[i][2] = __expf(yv[i].z); eyv[i][3] = __expf(yv[i].w);
        }

        // W = E·V, T = CE·V via MFMA
        f4 acc0 = {0.f, 0.f, 0.f, 0.f}, acc1 = acc0, acc2 = acc0, acc3 = acc0, tac = acc0;
        const _Float16* Vc = &Vb[cur][0][0] + bl * VSTR + g * 8;
        #pragma unroll
        for (int kt = 0; kt < 8; ++kt) {
            h8 bf = *(const h8*)(Vc + kt * 32);   // B-frag: n=bl, k=kt*32+g*8+j
            acc0 = MFMA16(ea[0][kt], bf, acc0);
            acc1 = MFMA16(ea[1][kt], bf, acc1);
            acc2 = MFMA16(ea[2][kt], bf, acc2);
            acc3 = MFMA16(ea[3][kt], bf, acc3);
            tac  = MFMA16(at[kt],    bf, tac);
        }

        // prefetch t+1 (clamped)
        const int tn = (t + 1 < TT) ? t + 1 : TT - 1;
        float4 yn[4];
        #pragma unroll
        for (int i = 0; i < 4; ++i)
            yn[i] = *(const float4*)(ybase + (size_t)tn * KK + (w * 4 + i) * 16 + g * 4);
        float mn = mbase[tn];

        // normalize, apply emissions, masked select, store
        const float Tb  = tac[0];                       // all regs/rows identical
        const float inv = __builtin_amdgcn_rcpf(Tb);
        const bool  msk = (mv > 0.5f);

        f4 accs[4] = {acc0, acc1, acc2, acc3};
        #pragma unroll
        for (int i = 0; i < 4; ++i) {
            h4 nv;
            #pragma unroll
            for (int r = 0; r < 4; ++r) nv[r] = (_Float16)(accs[i][r] * eyv[i][r] * inv);
            h4 sv = msk ? nv : keep[i];
            keep[i] = sv;
            const int k0w = (w * 4 + i) * 16 + g * 4;
            *(h4*)(&Vb[cur ^ 1][bl][k0w]) = sv;         // 8B aligned ds_write_b64
        }
        Lam += msk ? __logf(Tb) : 0.f;

        #pragma unroll
        for (int i = 0; i < 4; ++i) yv[i] = yn[i];
        mv = mn;
        cur ^= 1;
        __syncthreads();   // single barrier per step
    }

    // ---- final: S_b = sum_k V[k,b] via ones-A MFMA (all lanes get S_b)
    h8 ones8;
    #pragma unroll
    for (int j = 0; j < 8; ++j) ones8[j] = (_Float16)1.f;
    f4 sac = {0.f, 0.f, 0.f, 0.f};
    const _Float16* Vc = &Vb[cur][0][0] + bl * VSTR + g * 8;
    #pragma unroll
    for (int kt = 0; kt < 8; ++kt) {
        h8 bf = *(const h8*)(Vc + kt * 32);
        sac = MFMA16(ones8, bf, sac);
    }
    if (tid < NB) out[b0 + tid] = __logf(sac[0]) + Lam;
}

extern "C" void kernel_launch(void* const* d_in, const int* in_sizes, int n_in,
                              void* d_out, int out_size, void* d_ws, size_t ws_size,
                              hipStream_t stream) {
    const float* y     = (const float*)d_in[0];   // (B, T, K) fp32
    const float* mask  = (const float*)d_in[1];   // (B, T)    fp32
    const float* trans = (const float*)d_in[2];   // (K, K)    fp32
    float* out = (float*)d_out;                   // (B,)      fp32
    const int B = in_sizes[1] / TT;
    crf_fwd_kernel<<<B / NB, 256, 0, stream>>>(y, mask, trans, out);
}